// Round 4
// baseline (350.388 us; speedup 1.0000x reference)
//
#include <hip/hip_runtime.h>
#include <cstdint>
#include <cstddef>

typedef _Float16 f16;
typedef _Float16 half4 __attribute__((ext_vector_type(4)));
typedef _Float16 half8 __attribute__((ext_vector_type(8)));
typedef __fp16 fp16x2 __attribute__((ext_vector_type(2)));
typedef float f32x4 __attribute__((ext_vector_type(4)));

#define BN_EPS 1e-5f

#if defined(__has_builtin)
# if __has_builtin(__builtin_amdgcn_fdot2)
#  define HAVE_FDOT2 1
# endif
#endif
#ifndef HAVE_FDOT2
# define HAVE_FDOT2 0
#endif

// ---------------- workspace layout (bytes) ----------------
static constexpr size_t OFF_XB  = 0;          // f16 [64][32][32][256] NHWC      33,554,432
static constexpr size_t OFF_ZB  = 33554432;   // f16 [64][16][16][256] NHWC       8,388,608
static constexpr size_t OFF_WX  = 41943040;   // f16 [9][256][256]                1,179,648
static constexpr size_t OFF_WZ  = 43122688;   // f16 [9][256][256]                1,179,648
static constexpr size_t OFF_BNX = 44302336;   // f32 scale[256], bias[256]            2,048
static constexpr size_t OFF_BNZ = 44304384;   //                                      2,048
static constexpr size_t OFF_XFH = 44306432;   // f16 [16384][30][32]             31,457,280
static constexpr size_t OFF_ZFH = 75763712;   // f16 [16384][14][16]              7,340,032

// ---------------- fused prep: transposes + weight repack + BN fold ----------------
// (unchanged this round — attribution: delta isolates conv)
__global__ __launch_bounds__(256) void prep_all(
    const float* __restrict__ x, const float* __restrict__ z,
    const float* __restrict__ w_x, const float* __restrict__ w_z,
    const float* __restrict__ gx, const float* __restrict__ bx,
    const float* __restrict__ mx, const float* __restrict__ vx,
    const float* __restrict__ gz, const float* __restrict__ bz,
    const float* __restrict__ mz, const float* __restrict__ vz,
    f16* __restrict__ xb, f16* __restrict__ zb,
    f16* __restrict__ wxA, f16* __restrict__ wzA,
    float* __restrict__ bnx, float* __restrict__ bnz) {
  __shared__ float tile[64][33];              // image transpose staging
  __shared__ alignas(16) f16 wtile[2304];     // weight repack staging [khw][cin]
  const int bid = blockIdx.x;
  const int tid = threadIdx.x;
  if (bid < 12288) {
    const float* src; f16* dst; int lw, r;
    if (bid < 8192) { src = x; dst = xb; lw = 5; r = bid; }
    else            { src = z; dst = zb; lw = 4; r = bid - 8192; }
    const int W = 1 << lw;
    const int c0 = (r & 3) << 6;
    const int h = (r >> 2) & (W - 1);
    const int b = (r >> 2) >> lw;
    const float* sp = src + ((size_t)((b << 8) + c0) << (2 * lw)) + ((size_t)h << lw);
    const int w4 = W >> 2;
    const int n1 = w4 << 6;
    for (int i = tid; i < n1; i += 256) {
      int cl = i >> (lw - 2), c4 = i & (w4 - 1);
      float4 v = *(const float4*)(sp + ((size_t)cl << (2 * lw)) + (c4 << 2));
      int w0 = c4 << 2;
      tile[cl][w0] = v.x; tile[cl][w0 + 1] = v.y;
      tile[cl][w0 + 2] = v.z; tile[cl][w0 + 3] = v.w;
    }
    __syncthreads();
    f16* dp = dst + ((size_t)((b << lw) + h) << lw << 8) + c0;
    const int n2 = W << 3;
    for (int j = tid; j < n2; j += 256) {
      int w = j >> 3, cl0 = (j & 7) << 3;
      half8 o;
#pragma unroll
      for (int e = 0; e < 8; ++e) o[e] = (f16)tile[cl0 + e][w];
      *(half8*)(dp + (w << 8) + cl0) = o;
    }
  } else if (bid < 12800) {
    int r = bid - 12288;
    const float* src = (r < 256) ? w_x : w_z;
    f16* dst = (r < 256) ? wxA : wzA;
    int cout = r & 255;
    const float* sp = src + (size_t)cout * 2304;
    for (int i = tid; i < 2304; i += 256) {
      int cin = i / 9, khw = i - cin * 9;
      wtile[khw * 256 + cin] = (f16)sp[i];
    }
    __syncthreads();
    for (int c = tid; c < 288; c += 256) {
      int khw = c >> 5, cin0 = (c & 31) << 3;
      *(half8*)(dst + (khw << 16) + (cout << 8) + cin0) =
          *(const half8*)(wtile + khw * 256 + cin0);
    }
  } else {
    int c = tid;
    float iv = gx[c] / sqrtf(vx[c] + BN_EPS);
    bnx[c] = iv;
    bnx[256 + c] = bx[c] - mx[c] * iv;
    float iz = gz[c] / sqrtf(vz[c] + BN_EPS);
    bnz[c] = iz;
    bnz[256 + c] = bz[c] - mz[c] * iz;
  }
}

// ---------------- unified implicit-im2col conv3x3 + BN (MFMA f16) ----------------
// v3: BK=32 double-buffer. LDS stays 32KB total (2 buf x (128x32 A + 128x32 B) f16)
// so occupancy is preserved at 5 blocks/CU, AND each K-step's global_load_lds are
// issued a full compute phase before the barrier that drains them (T3-min order).
// 72 K-steps, one barrier each (same barrier count as v1's 36x2).
// Swizzle for 64B rows (4 chunks of 16B): LDS chunk c holds global chunk
// c ^ ((row>>1)&3) — conflict-free for ds_read_b128 within 8-lane groups.
__device__ __forceinline__ void gl_lds16(const f16* g, f16* l) {
  __builtin_amdgcn_global_load_lds((__attribute__((address_space(1))) void*)g,
                                   (__attribute__((address_space(3))) void*)l, 16, 0, 0);
}

__global__ __launch_bounds__(256, 5) void conv_gemm_u(
    const f16* __restrict__ xb, const f16* __restrict__ zb,
    const f16* __restrict__ wx, const f16* __restrict__ wz,
    const float* __restrict__ bnx, const float* __restrict__ bnz,
    f16* __restrict__ xfh, f16* __restrict__ zfh) {
  __shared__ alignas(16) f16 As[2][128 * 32];  // [buf][cout_local][k32]
  __shared__ alignas(16) f16 Bs[2][128 * 32];  // [buf][n_local][k32]
  const int g = blockIdx.x;
  const int pairIdx = ((g >> 4) << 3) | (g & 7);
  const int mblk = (g >> 3) & 1;
  if (pairIdx >= 548) return;
  const f16* inp; const f16* wA; const float* bn; f16* out;
  int nblk, HIN, WIN, WOUT, NPIX, WPAD, OPLANE;
  if (pairIdx < 450) {
    inp = xb; wA = wx; bn = bnx; out = xfh; nblk = pairIdx;
    HIN = 32; WIN = 32; WOUT = 30; NPIX = 900; WPAD = 32; OPLANE = 960;
  } else {
    inp = zb; wA = wz; bn = bnz; out = zfh; nblk = pairIdx - 450;
    HIN = 16; WIN = 16; WOUT = 14; NPIX = 196; WPAD = 16; OPLANE = 224;
  }
  const int tid = threadIdx.x;
  const int wid = tid >> 6, lane = tid & 63;
  const int wm = (wid >> 1) << 6, wn = (wid & 1) << 6;
  const int q = lane >> 4, lm = lane & 15;
  // staging decomposition: one gl_lds = 1KB = 16 rows x 4 chunks of 16B
  const int sr = lane >> 2, sc = lane & 3;
  const int swz = ((sc ^ ((sr >> 1) & 3)) << 3);  // pre-swizzled global chunk (f16 elems)
  const int mbase = mblk << 7;

  int arow[2], brow[2];
#pragma unroll
  for (int l = 0; l < 2; ++l) {
    int rr = (wid << 5) + (l << 4) + sr;          // LDS-local row 0..127
    arow[l] = ((mbase + rr) << 8) + swz;
    int n = (nblk << 7) + rr;
    int b = n / NPIX, rem = n - b * NPIX;
    int oh = rem / WOUT, ow = rem - oh * WOUT;
    brow[l] = (((b * HIN + oh) * WIN + ow) << 8) + swz;
  }

  f32x4 acc[4][4] = {};
  const int cA0 = (q ^ ((lm >> 1) & 3)) << 3;     // read-side swizzled chunk

  auto STAGE = [&](int kt, int buf) {
    const int cinb = kt / 9;
    const int khw = kt - cinb * 9;
    const int cin0 = cinb << 5;
    const int kh = khw / 3, kw = khw - kh * 3;
    const int wofs = (khw << 16) + cin0;
    const int iofs = ((kh * WIN + kw) << 8) + cin0;
#pragma unroll
    for (int l = 0; l < 2; ++l) {
      const int ldso = (wid << 10) + (l << 9);    // row_start*32 f16 elems
      gl_lds16(wA + wofs + arow[l], &As[buf][ldso]);
      gl_lds16(inp + iofs + brow[l], &Bs[buf][ldso]);
    }
  };

  STAGE(0, 0);
  __syncthreads();                  // buf0 resident

  for (int kt = 0; kt < 72; ++kt) {
    const int buf = kt & 1;
    if (kt < 71) STAGE(kt + 1, buf ^ 1);  // in flight across this compute phase
    half8 af[4], bf[4];
#pragma unroll
    for (int f = 0; f < 4; ++f) {
      af[f] = *(const half8*)&As[buf][((wm + (f << 4) + lm) << 5) + cA0];
      bf[f] = *(const half8*)&Bs[buf][((wn + (f << 4) + lm) << 5) + cA0];
    }
#pragma unroll
    for (int fm = 0; fm < 4; ++fm)
#pragma unroll
      for (int fn = 0; fn < 4; ++fn)
        acc[fm][fn] =
            __builtin_amdgcn_mfma_f32_16x16x32_f16(af[fm], bf[fn], acc[fm][fn], 0, 0, 0);
    __syncthreads();                // drains prefetch (covered by the 16 MFMA above)
  }

  // epilogue: BN + f16 padded store. C/D: row m = q*4+reg, col n = lm.
#pragma unroll
  for (int fn = 0; fn < 4; ++fn) {
    int n_g = (nblk << 7) + wn + (fn << 4) + lm;
    int b = n_g / NPIX, rem = n_g - b * NPIX;
    int oh = rem / WOUT, ow = rem - oh * WOUT;
    f16* op = out + (size_t)(b << 8) * OPLANE + oh * WPAD + ow;
#pragma unroll
    for (int fm = 0; fm < 4; ++fm) {
      int m0 = mbase + wm + (fm << 4) + (q << 2);
#pragma unroll
      for (int rg = 0; rg < 4; ++rg) {
        int m = m0 + rg;
        op[(size_t)m * OPLANE] = (f16)(acc[fm][fn][rg] * bn[m] + bn[256 + m]);
      }
    }
  }
}

// ---------------- depthwise xcorr v4: fdot2 (unchanged this round) ----------------
static constexpr int XST = 40;
static constexpr int XCH = 30 * XST;
static constexpr int ZCH = 14 * 16;

__global__ __launch_bounds__(256) void xcorr_dw3(const f16* __restrict__ zfh,
                                                 const f16* __restrict__ xfh,
                                                 float* __restrict__ out) {
  __shared__ f16 xs[3 * XCH];
  __shared__ f16 zs[3 * ZCH];
  const int t = threadIdx.x;
  const int ch0 = blockIdx.x * 3;

  for (int i = t; i < 360; i += 256) {
    int ch = i / 120, rem = i - ch * 120;
    int row = rem >> 2, col = (rem & 3) << 3;
    if (ch0 + ch < 16384)
      *(half8*)(xs + ch * XCH + row * XST + col) =
          *(const half8*)(xfh + (size_t)(ch0 + ch) * 960 + row * 32 + col);
  }
  for (int i = t; i < 84; i += 256) {
    int ch = i / 28, rem = i - ch * 28;
    if (ch0 + ch < 16384)
      *(half8*)(zs + ch * ZCH + rem * 8) =
          *(const half8*)(zfh + (size_t)(ch0 + ch) * 224 + rem * 8);
  }
  __syncthreads();

  int lc = t / 85;
  int r = t - lc * 85;
  const bool ok = (lc < 3) && (ch0 + lc < 16384);
  if (lc > 2) lc = 2;
  const int oy = r / 5, oxq = r - oy * 5, ox0 = oxq * 4;
  const f16* xbp = xs + lc * XCH;
  const f16* zbp = zs + lc * ZCH;

  float acc[4] = {0.f, 0.f, 0.f, 0.f};

#if HAVE_FDOT2
  union X20 { half4 v4[5]; fp16x2 h2[10]; };
  union Z16 { half8 v8[2]; fp16x2 h2[8]; };
#pragma unroll 2
  for (int u = 0; u < 14; ++u) {
    X20 xl;
#pragma unroll
    for (int k = 0; k < 5; ++k)
      xl.v4[k] = *(const half4*)(xbp + (oy + u) * XST + ox0 + (k << 2));
    Z16 zl;
    zl.v8[0] = *(const half8*)(zbp + u * 16);
    zl.v8[1] = *(const half8*)(zbp + u * 16 + 8);
    fp16x2 xo[8];
#pragma unroll
    for (int m = 0; m < 8; ++m) { xo[m][0] = xl.h2[m][1]; xo[m][1] = xl.h2[m + 1][0]; }
#pragma unroll
    for (int k = 0; k < 7; ++k) {
      acc[0] = __builtin_amdgcn_fdot2(zl.h2[k], xl.h2[k],     acc[0], false);
      acc[1] = __builtin_amdgcn_fdot2(zl.h2[k], xo[k],        acc[1], false);
      acc[2] = __builtin_amdgcn_fdot2(zl.h2[k], xl.h2[k + 1], acc[2], false);
      acc[3] = __builtin_amdgcn_fdot2(zl.h2[k], xo[k + 1],    acc[3], false);
    }
  }
#else
#pragma unroll 2
  for (int u = 0; u < 14; ++u) {
    float xr[20];
#pragma unroll
    for (int k = 0; k < 5; ++k) {
      half4 h = *(const half4*)(xbp + (oy + u) * XST + ox0 + k * 4);
#pragma unroll
      for (int e = 0; e < 4; ++e) xr[k * 4 + e] = (float)h[e];
    }
    float zc[14];
    {
      half8 z0 = *(const half8*)(zbp + u * 16);
      half8 z1 = *(const half8*)(zbp + u * 16 + 8);
#pragma unroll
      for (int e = 0; e < 8; ++e) zc[e] = (float)z0[e];
#pragma unroll
      for (int e = 0; e < 6; ++e) zc[8 + e] = (float)z1[e];
    }
#pragma unroll
    for (int v = 0; v < 14; ++v)
#pragma unroll
      for (int j = 0; j < 4; ++j) acc[j] = fmaf(zc[v], xr[v + j], acc[j]);
  }
#endif

  if (ok) {
    float* op = out + (size_t)(ch0 + lc) * 289 + oy * 17;
#pragma unroll
    for (int j = 0; j < 4; ++j) {
      int ox = ox0 + j;
      if (ox < 17) op[ox] = acc[j];
    }
  }
}

extern "C" void kernel_launch(void* const* d_in, const int* in_sizes, int n_in,
                              void* d_out, int out_size, void* d_ws, size_t ws_size,
                              hipStream_t stream) {
  const float* z = (const float*)d_in[0];
  const float* x = (const float*)d_in[1];
  const float* w_z = (const float*)d_in[2];
  const float* w_x = (const float*)d_in[3];
  const float* gamma_z = (const float*)d_in[4];
  const float* beta_z = (const float*)d_in[5];
  const float* mean_z = (const float*)d_in[6];
  const float* var_z = (const float*)d_in[7];
  const float* gamma_x = (const float*)d_in[8];
  const float* beta_x = (const float*)d_in[9];
  const float* mean_x = (const float*)d_in[10];
  const float* var_x = (const float*)d_in[11];

  char* ws = (char*)d_ws;
  f16* xb = (f16*)(ws + OFF_XB);
  f16* zb = (f16*)(ws + OFF_ZB);
  f16* wxA = (f16*)(ws + OFF_WX);
  f16* wzA = (f16*)(ws + OFF_WZ);
  float* bnx = (float*)(ws + OFF_BNX);
  float* bnz = (float*)(ws + OFF_BNZ);
  f16* xfh = (f16*)(ws + OFF_XFH);
  f16* zfh = (f16*)(ws + OFF_ZFH);
  float* out = (float*)d_out;

  prep_all<<<12801, 256, 0, stream>>>(x, z, w_x, w_z,
                                      gamma_x, beta_x, mean_x, var_x,
                                      gamma_z, beta_z, mean_z, var_z,
                                      xb, zb, wxA, wzA, bnx, bnz);

  // 548 (pair) x 2 (mblk) tiles, padded to 1104 = 69*16 for the XCD permutation
  conv_gemm_u<<<1104, 256, 0, stream>>>(xb, zb, wxA, wzA, bnx, bnz, xfh, zfh);

  xcorr_dw3<<<(16384 + 2) / 3, 256, 0, stream>>>(zfh, xfh, out);
}

// Round 5
// 287.412 us; speedup vs baseline: 1.2191x; 1.2191x over previous
//
#include <hip/hip_runtime.h>
#include <cstdint>
#include <cstddef>

typedef _Float16 f16;
typedef _Float16 half4 __attribute__((ext_vector_type(4)));
typedef _Float16 half8 __attribute__((ext_vector_type(8)));
typedef __fp16 fp16x2 __attribute__((ext_vector_type(2)));
typedef float f32x4 __attribute__((ext_vector_type(4)));

#define BN_EPS 1e-5f

#if defined(__has_builtin)
# if __has_builtin(__builtin_amdgcn_fdot2)
#  define HAVE_FDOT2 1
# endif
#endif
#ifndef HAVE_FDOT2
# define HAVE_FDOT2 0
#endif

// ---------------- workspace layout (bytes) ----------------
static constexpr size_t OFF_XB  = 0;          // f16 [64][32][32][256] NHWC      33,554,432
static constexpr size_t OFF_ZB  = 33554432;   // f16 [64][16][16][256] NHWC       8,388,608
static constexpr size_t OFF_WX  = 41943040;   // f16 [9][256][256]                1,179,648
static constexpr size_t OFF_WZ  = 43122688;   // f16 [9][256][256]                1,179,648
static constexpr size_t OFF_BNX = 44302336;   // f32 scale[256], bias[256]            2,048
static constexpr size_t OFF_BNZ = 44304384;   //                                      2,048
static constexpr size_t OFF_XFH = 44306432;   // f16 [16384][30][32]             31,457,280
static constexpr size_t OFF_ZFH = 75763712;   // f16 [16384][14][16]              7,340,032

// ---------------- fused prep: transposes + weight repack + BN fold ----------------
// (unchanged — attribution: delta isolates conv)
__global__ __launch_bounds__(256) void prep_all(
    const float* __restrict__ x, const float* __restrict__ z,
    const float* __restrict__ w_x, const float* __restrict__ w_z,
    const float* __restrict__ gx, const float* __restrict__ bx,
    const float* __restrict__ mx, const float* __restrict__ vx,
    const float* __restrict__ gz, const float* __restrict__ bz,
    const float* __restrict__ mz, const float* __restrict__ vz,
    f16* __restrict__ xb, f16* __restrict__ zb,
    f16* __restrict__ wxA, f16* __restrict__ wzA,
    float* __restrict__ bnx, float* __restrict__ bnz) {
  __shared__ float tile[64][33];              // image transpose staging
  __shared__ alignas(16) f16 wtile[2304];     // weight repack staging [khw][cin]
  const int bid = blockIdx.x;
  const int tid = threadIdx.x;
  if (bid < 12288) {
    const float* src; f16* dst; int lw, r;
    if (bid < 8192) { src = x; dst = xb; lw = 5; r = bid; }
    else            { src = z; dst = zb; lw = 4; r = bid - 8192; }
    const int W = 1 << lw;
    const int c0 = (r & 3) << 6;
    const int h = (r >> 2) & (W - 1);
    const int b = (r >> 2) >> lw;
    const float* sp = src + ((size_t)((b << 8) + c0) << (2 * lw)) + ((size_t)h << lw);
    const int w4 = W >> 2;
    const int n1 = w4 << 6;
    for (int i = tid; i < n1; i += 256) {
      int cl = i >> (lw - 2), c4 = i & (w4 - 1);
      float4 v = *(const float4*)(sp + ((size_t)cl << (2 * lw)) + (c4 << 2));
      int w0 = c4 << 2;
      tile[cl][w0] = v.x; tile[cl][w0 + 1] = v.y;
      tile[cl][w0 + 2] = v.z; tile[cl][w0 + 3] = v.w;
    }
    __syncthreads();
    f16* dp = dst + ((size_t)((b << lw) + h) << lw << 8) + c0;
    const int n2 = W << 3;
    for (int j = tid; j < n2; j += 256) {
      int w = j >> 3, cl0 = (j & 7) << 3;
      half8 o;
#pragma unroll
      for (int e = 0; e < 8; ++e) o[e] = (f16)tile[cl0 + e][w];
      *(half8*)(dp + (w << 8) + cl0) = o;
    }
  } else if (bid < 12800) {
    int r = bid - 12288;
    const float* src = (r < 256) ? w_x : w_z;
    f16* dst = (r < 256) ? wxA : wzA;
    int cout = r & 255;
    const float* sp = src + (size_t)cout * 2304;
    for (int i = tid; i < 2304; i += 256) {
      int cin = i / 9, khw = i - cin * 9;
      wtile[khw * 256 + cin] = (f16)sp[i];
    }
    __syncthreads();
    for (int c = tid; c < 288; c += 256) {
      int khw = c >> 5, cin0 = (c & 31) << 3;
      *(half8*)(dst + (khw << 16) + (cout << 8) + cin0) =
          *(const half8*)(wtile + khw * 256 + cin0);
    }
  } else {
    int c = tid;
    float iv = gx[c] / sqrtf(vx[c] + BN_EPS);
    bnx[c] = iv;
    bnx[256 + c] = bx[c] - mx[c] * iv;
    float iz = gz[c] / sqrtf(vz[c] + BN_EPS);
    bnz[c] = iz;
    bnz[256 + c] = bz[c] - mz[c] * iz;
  }
}

// ---------------- unified implicit-im2col conv3x3 + BN (MFMA f16) ----------------
// v4: BK=64 double-buffer + COUNTED vmcnt (T4). Unlike v2 (__syncthreads drained
// vmcnt(0) every barrier — no overlap), the wait for kt+1's loads happens one full
// K-step after issue, and kt+2's 8 loads stay in flight across the barrier.
// Per K-step:  COMPUTE(buf) ; s_barrier ; STAGE(kt+2 -> buf) ; vmcnt(8) ; s_barrier.
// vmcnt(8): 16 outstanding (kt+1:8 oldest, kt+2:8 newest) -> waits oldest 8 only.
// Own-vmcnt BEFORE barrier: waves read rows staged by other waves, so each wave's
// completion must precede the global rendezvous.
__device__ __forceinline__ void gl_lds16(const f16* g, f16* l) {
  __builtin_amdgcn_global_load_lds((__attribute__((address_space(1))) void*)g,
                                   (__attribute__((address_space(3))) void*)l, 16, 0, 0);
}
#define VMCNT(n) asm volatile("s_waitcnt vmcnt(" #n ")" ::: "memory")
#define BAR() __builtin_amdgcn_s_barrier()

__global__ __launch_bounds__(256, 2) void conv_gemm_u(
    const f16* __restrict__ xb, const f16* __restrict__ zb,
    const f16* __restrict__ wx, const f16* __restrict__ wz,
    const float* __restrict__ bnx, const float* __restrict__ bnz,
    f16* __restrict__ xfh, f16* __restrict__ zfh) {
  __shared__ f16 As[2][128 * 64];  // [buf][cout_local][k64], XOR-swizzled 16B chunks
  __shared__ f16 Bs[2][128 * 64];  // [buf][n_local][k64]
  const int g = blockIdx.x;
  const int pairIdx = ((g >> 4) << 3) | (g & 7);
  const int mblk = (g >> 3) & 1;
  if (pairIdx >= 548) return;
  const f16* inp; const f16* wA; const float* bn; f16* out;
  int nblk, HIN, WIN, WOUT, NPIX, WPAD, OPLANE;
  if (pairIdx < 450) {
    inp = xb; wA = wx; bn = bnx; out = xfh; nblk = pairIdx;
    HIN = 32; WIN = 32; WOUT = 30; NPIX = 900; WPAD = 32; OPLANE = 960;
  } else {
    inp = zb; wA = wz; bn = bnz; out = zfh; nblk = pairIdx - 450;
    HIN = 16; WIN = 16; WOUT = 14; NPIX = 196; WPAD = 16; OPLANE = 224;
  }
  const int tid = threadIdx.x;
  const int wid = tid >> 6, lane = tid & 63;
  const int wm = (wid >> 1) << 6, wn = (wid & 1) << 6;
  const int q = lane >> 4, lm = lane & 15;
  const int sr = lane >> 3, sc = lane & 7;
  const int swz = (sc ^ sr) << 3;
  const int mbase = mblk << 7;

  int arow[4], brow[4];
#pragma unroll
  for (int l = 0; l < 4; ++l) {
    int rr = (wid << 5) + (l << 3) + sr;
    arow[l] = ((mbase + rr) << 8) + swz;
    int n = (nblk << 7) + rr;
    int b = n / NPIX, rem = n - b * NPIX;
    int oh = rem / WOUT, ow = rem - oh * WOUT;
    brow[l] = (((b * HIN + oh) * WIN + ow) << 8) + swz;
  }

  f32x4 acc[4][4] = {};
  const int cA0 = (q ^ (lm & 7)) << 3;

  // stage K-step kt into buffer buf: 8 gl_lds per thread (A:4, B:4)
  auto STAGE = [&](int kt, int buf) {
    const int cinb = kt / 9;
    const int khw = kt - cinb * 9;
    const int cin0 = cinb << 6;
    const int kh = khw / 3, kw = khw - kh * 3;
    const int wofs = (khw << 16) + cin0;
    const int iofs = ((kh * WIN + kw) << 8) + cin0;
#pragma unroll
    for (int l = 0; l < 4; ++l) {
      const int ldso = ((wid << 5) + (l << 3)) << 6;
      gl_lds16(wA + wofs + arow[l], &As[buf][ldso]);
      gl_lds16(inp + iofs + brow[l], &Bs[buf][ldso]);
    }
  };

  auto COMPUTE = [&](int buf) {
#pragma unroll
    for (int h = 0; h < 2; ++h) {
      const int co = cA0 ^ (h << 5);
      half8 af[4], bf[4];
#pragma unroll
      for (int f = 0; f < 4; ++f) {
        af[f] = *(const half8*)&As[buf][((wm + (f << 4) + lm) << 6) + co];
        bf[f] = *(const half8*)&Bs[buf][((wn + (f << 4) + lm) << 6) + co];
      }
#pragma unroll
      for (int fm = 0; fm < 4; ++fm)
#pragma unroll
        for (int fn = 0; fn < 4; ++fn)
          acc[fm][fn] =
              __builtin_amdgcn_mfma_f32_16x16x32_f16(af[fm], bf[fn], acc[fm][fn], 0, 0, 0);
    }
  };

  // prologue: fill both buffers; wait only the oldest 8 (buf0)
  STAGE(0, 0);
  STAGE(1, 1);
  VMCNT(8);
  BAR();

  for (int kt = 0; kt < 34; ++kt) {
    const int buf = kt & 1;
    COMPUTE(buf);
    BAR();                 // all waves done reading buf
    STAGE(kt + 2, buf);    // overwrite buf; rides across the next barrier
    VMCNT(8);              // kt+1's 8 loads (oldest) complete; kt+2's 8 in flight
    BAR();                 // all waves' kt+1 loads complete -> buf^1 resident
  }
  // kt = 34: compute buf0; then drain kt35's loads fully (nothing behind them)
  COMPUTE(0);
  BAR();
  VMCNT(0);
  BAR();
  // kt = 35
  COMPUTE(1);

  // epilogue: BN + f16 padded store. C/D: row m = q*4+reg, col n = lm.
#pragma unroll
  for (int fn = 0; fn < 4; ++fn) {
    int n_g = (nblk << 7) + wn + (fn << 4) + lm;
    int b = n_g / NPIX, rem = n_g - b * NPIX;
    int oh = rem / WOUT, ow = rem - oh * WOUT;
    f16* op = out + (size_t)(b << 8) * OPLANE + oh * WPAD + ow;
#pragma unroll
    for (int fm = 0; fm < 4; ++fm) {
      int m0 = mbase + wm + (fm << 4) + (q << 2);
#pragma unroll
      for (int rg = 0; rg < 4; ++rg) {
        int m = m0 + rg;
        op[(size_t)m * OPLANE] = (f16)(acc[fm][fn][rg] * bn[m] + bn[256 + m]);
      }
    }
  }
}

// ---------------- depthwise xcorr v4: fdot2 (unchanged) ----------------
static constexpr int XST = 40;
static constexpr int XCH = 30 * XST;
static constexpr int ZCH = 14 * 16;

__global__ __launch_bounds__(256) void xcorr_dw3(const f16* __restrict__ zfh,
                                                 const f16* __restrict__ xfh,
                                                 float* __restrict__ out) {
  __shared__ f16 xs[3 * XCH];
  __shared__ f16 zs[3 * ZCH];
  const int t = threadIdx.x;
  const int ch0 = blockIdx.x * 3;

  for (int i = t; i < 360; i += 256) {
    int ch = i / 120, rem = i - ch * 120;
    int row = rem >> 2, col = (rem & 3) << 3;
    if (ch0 + ch < 16384)
      *(half8*)(xs + ch * XCH + row * XST + col) =
          *(const half8*)(xfh + (size_t)(ch0 + ch) * 960 + row * 32 + col);
  }
  for (int i = t; i < 84; i += 256) {
    int ch = i / 28, rem = i - ch * 28;
    if (ch0 + ch < 16384)
      *(half8*)(zs + ch * ZCH + rem * 8) =
          *(const half8*)(zfh + (size_t)(ch0 + ch) * 224 + rem * 8);
  }
  __syncthreads();

  int lc = t / 85;
  int r = t - lc * 85;
  const bool ok = (lc < 3) && (ch0 + lc < 16384);
  if (lc > 2) lc = 2;
  const int oy = r / 5, oxq = r - oy * 5, ox0 = oxq * 4;
  const f16* xbp = xs + lc * XCH;
  const f16* zbp = zs + lc * ZCH;

  float acc[4] = {0.f, 0.f, 0.f, 0.f};

#if HAVE_FDOT2
  union X20 { half4 v4[5]; fp16x2 h2[10]; };
  union Z16 { half8 v8[2]; fp16x2 h2[8]; };
#pragma unroll 2
  for (int u = 0; u < 14; ++u) {
    X20 xl;
#pragma unroll
    for (int k = 0; k < 5; ++k)
      xl.v4[k] = *(const half4*)(xbp + (oy + u) * XST + ox0 + (k << 2));
    Z16 zl;
    zl.v8[0] = *(const half8*)(zbp + u * 16);
    zl.v8[1] = *(const half8*)(zbp + u * 16 + 8);
    fp16x2 xo[8];
#pragma unroll
    for (int m = 0; m < 8; ++m) { xo[m][0] = xl.h2[m][1]; xo[m][1] = xl.h2[m + 1][0]; }
#pragma unroll
    for (int k = 0; k < 7; ++k) {
      acc[0] = __builtin_amdgcn_fdot2(zl.h2[k], xl.h2[k],     acc[0], false);
      acc[1] = __builtin_amdgcn_fdot2(zl.h2[k], xo[k],        acc[1], false);
      acc[2] = __builtin_amdgcn_fdot2(zl.h2[k], xl.h2[k + 1], acc[2], false);
      acc[3] = __builtin_amdgcn_fdot2(zl.h2[k], xo[k + 1],    acc[3], false);
    }
  }
#else
#pragma unroll 2
  for (int u = 0; u < 14; ++u) {
    float xr[20];
#pragma unroll
    for (int k = 0; k < 5; ++k) {
      half4 h = *(const half4*)(xbp + (oy + u) * XST + ox0 + k * 4);
#pragma unroll
      for (int e = 0; e < 4; ++e) xr[k * 4 + e] = (float)h[e];
    }
    float zc[14];
    {
      half8 z0 = *(const half8*)(zbp + u * 16);
      half8 z1 = *(const half8*)(zbp + u * 16 + 8);
#pragma unroll
      for (int e = 0; e < 8; ++e) zc[e] = (float)z0[e];
#pragma unroll
      for (int e = 0; e < 6; ++e) zc[8 + e] = (float)z1[e];
    }
#pragma unroll
    for (int v = 0; v < 14; ++v)
#pragma unroll
      for (int j = 0; j < 4; ++j) acc[j] = fmaf(zc[v], xr[v + j], acc[j]);
  }
#endif

  if (ok) {
    float* op = out + (size_t)(ch0 + lc) * 289 + oy * 17;
#pragma unroll
    for (int j = 0; j < 4; ++j) {
      int ox = ox0 + j;
      if (ox < 17) op[ox] = acc[j];
    }
  }
}

extern "C" void kernel_launch(void* const* d_in, const int* in_sizes, int n_in,
                              void* d_out, int out_size, void* d_ws, size_t ws_size,
                              hipStream_t stream) {
  const float* z = (const float*)d_in[0];
  const float* x = (const float*)d_in[1];
  const float* w_z = (const float*)d_in[2];
  const float* w_x = (const float*)d_in[3];
  const float* gamma_z = (const float*)d_in[4];
  const float* beta_z = (const float*)d_in[5];
  const float* mean_z = (const float*)d_in[6];
  const float* var_z = (const float*)d_in[7];
  const float* gamma_x = (const float*)d_in[8];
  const float* beta_x = (const float*)d_in[9];
  const float* mean_x = (const float*)d_in[10];
  const float* var_x = (const float*)d_in[11];

  char* ws = (char*)d_ws;
  f16* xb = (f16*)(ws + OFF_XB);
  f16* zb = (f16*)(ws + OFF_ZB);
  f16* wxA = (f16*)(ws + OFF_WX);
  f16* wzA = (f16*)(ws + OFF_WZ);
  float* bnx = (float*)(ws + OFF_BNX);
  float* bnz = (float*)(ws + OFF_BNZ);
  f16* xfh = (f16*)(ws + OFF_XFH);
  f16* zfh = (f16*)(ws + OFF_ZFH);
  float* out = (float*)d_out;

  prep_all<<<12801, 256, 0, stream>>>(x, z, w_x, w_z,
                                      gamma_x, beta_x, mean_x, var_x,
                                      gamma_z, beta_z, mean_z, var_z,
                                      xb, zb, wxA, wzA, bnx, bnz);

  // 548 (pair) x 2 (mblk) tiles, padded to 1104 = 69*16 for the XCD permutation
  conv_gemm_u<<<1104, 256, 0, stream>>>(xb, zb, wxA, wzA, bnx, bnz, xfh, zfh);

  xcorr_dw3<<<(16384 + 2) / 3, 256, 0, stream>>>(zfh, xfh, out);
}

// Round 6
// 273.749 us; speedup vs baseline: 1.2800x; 1.0499x over previous
//
#include <hip/hip_runtime.h>
#include <cstdint>
#include <cstddef>

typedef _Float16 f16;
typedef _Float16 half4 __attribute__((ext_vector_type(4)));
typedef _Float16 half8 __attribute__((ext_vector_type(8)));
typedef __fp16 fp16x2 __attribute__((ext_vector_type(2)));
typedef float f32x4 __attribute__((ext_vector_type(4)));

#define BN_EPS 1e-5f

#if defined(__has_builtin)
# if __has_builtin(__builtin_amdgcn_fdot2)
#  define HAVE_FDOT2 1
# endif
#endif
#ifndef HAVE_FDOT2
# define HAVE_FDOT2 0
#endif

// ---------------- workspace layout (bytes) ----------------
static constexpr size_t OFF_XB  = 0;          // f16 [64][32][32][256] NHWC      33,554,432
static constexpr size_t OFF_ZB  = 33554432;   // f16 [64][16][16][256] NHWC       8,388,608
static constexpr size_t OFF_WX  = 41943040;   // f16 [9][256][256]                1,179,648
static constexpr size_t OFF_WZ  = 43122688;   // f16 [9][256][256]                1,179,648
static constexpr size_t OFF_BNX = 44302336;   // f32 scale[256], bias[256]            2,048
static constexpr size_t OFF_BNZ = 44304384;   //                                      2,048
static constexpr size_t OFF_XFH = 44306432;   // f16 [16384][30][32]             31,457,280
static constexpr size_t OFF_ZFH = 75763712;   // f16 [16384][14][16]              7,340,032

// ---------------- fused prep: transposes + weight repack + BN fold ----------------
// (unchanged — attribution: delta isolates xcorr)
__global__ __launch_bounds__(256) void prep_all(
    const float* __restrict__ x, const float* __restrict__ z,
    const float* __restrict__ w_x, const float* __restrict__ w_z,
    const float* __restrict__ gx, const float* __restrict__ bx,
    const float* __restrict__ mx, const float* __restrict__ vx,
    const float* __restrict__ gz, const float* __restrict__ bz,
    const float* __restrict__ mz, const float* __restrict__ vz,
    f16* __restrict__ xb, f16* __restrict__ zb,
    f16* __restrict__ wxA, f16* __restrict__ wzA,
    float* __restrict__ bnx, float* __restrict__ bnz) {
  __shared__ float tile[64][33];              // image transpose staging
  __shared__ alignas(16) f16 wtile[2304];     // weight repack staging [khw][cin]
  const int bid = blockIdx.x;
  const int tid = threadIdx.x;
  if (bid < 12288) {
    const float* src; f16* dst; int lw, r;
    if (bid < 8192) { src = x; dst = xb; lw = 5; r = bid; }
    else            { src = z; dst = zb; lw = 4; r = bid - 8192; }
    const int W = 1 << lw;
    const int c0 = (r & 3) << 6;
    const int h = (r >> 2) & (W - 1);
    const int b = (r >> 2) >> lw;
    const float* sp = src + ((size_t)((b << 8) + c0) << (2 * lw)) + ((size_t)h << lw);
    const int w4 = W >> 2;
    const int n1 = w4 << 6;
    for (int i = tid; i < n1; i += 256) {
      int cl = i >> (lw - 2), c4 = i & (w4 - 1);
      float4 v = *(const float4*)(sp + ((size_t)cl << (2 * lw)) + (c4 << 2));
      int w0 = c4 << 2;
      tile[cl][w0] = v.x; tile[cl][w0 + 1] = v.y;
      tile[cl][w0 + 2] = v.z; tile[cl][w0 + 3] = v.w;
    }
    __syncthreads();
    f16* dp = dst + ((size_t)((b << lw) + h) << lw << 8) + c0;
    const int n2 = W << 3;
    for (int j = tid; j < n2; j += 256) {
      int w = j >> 3, cl0 = (j & 7) << 3;
      half8 o;
#pragma unroll
      for (int e = 0; e < 8; ++e) o[e] = (f16)tile[cl0 + e][w];
      *(half8*)(dp + (w << 8) + cl0) = o;
    }
  } else if (bid < 12800) {
    int r = bid - 12288;
    const float* src = (r < 256) ? w_x : w_z;
    f16* dst = (r < 256) ? wxA : wzA;
    int cout = r & 255;
    const float* sp = src + (size_t)cout * 2304;
    for (int i = tid; i < 2304; i += 256) {
      int cin = i / 9, khw = i - cin * 9;
      wtile[khw * 256 + cin] = (f16)sp[i];
    }
    __syncthreads();
    for (int c = tid; c < 288; c += 256) {
      int khw = c >> 5, cin0 = (c & 31) << 3;
      *(half8*)(dst + (khw << 16) + (cout << 8) + cin0) =
          *(const half8*)(wtile + khw * 256 + cin0);
    }
  } else {
    int c = tid;
    float iv = gx[c] / sqrtf(vx[c] + BN_EPS);
    bnx[c] = iv;
    bnx[256 + c] = bx[c] - mx[c] * iv;
    float iz = gz[c] / sqrtf(vz[c] + BN_EPS);
    bnz[c] = iz;
    bnz[256 + c] = bz[c] - mz[c] * iz;
  }
}

// ---------------- unified implicit-im2col conv3x3 + BN (MFMA f16), BK=64 ----------------
// REVERTED to the round-2 structure (measured 111.5us): single-buffer 32KB LDS,
// 4 blocks/CU — block-level TLP beats explicit pipelining here (r3/r4/r5 all lost:
// 135/175/117us; depth-1 drain, BK=32 fetch-amplification, counted-vmcnt@2blk).
__device__ __forceinline__ void gl_lds16(const f16* g, f16* l) {
  __builtin_amdgcn_global_load_lds((__attribute__((address_space(1))) void*)g,
                                   (__attribute__((address_space(3))) void*)l, 16, 0, 0);
}

__global__ __launch_bounds__(256, 4) void conv_gemm_u(
    const f16* __restrict__ xb, const f16* __restrict__ zb,
    const f16* __restrict__ wx, const f16* __restrict__ wz,
    const float* __restrict__ bnx, const float* __restrict__ bnz,
    f16* __restrict__ xfh, f16* __restrict__ zfh) {
  __shared__ f16 As[128 * 64];  // [cout_local][k64]  rows of 128B, XOR-swizzled 16B chunks
  __shared__ f16 Bs[128 * 64];  // [n_local][k64]
  const int g = blockIdx.x;
  const int pairIdx = ((g >> 4) << 3) | (g & 7);
  const int mblk = (g >> 3) & 1;
  if (pairIdx >= 548) return;
  const f16* inp; const f16* wA; const float* bn; f16* out;
  int nblk, HIN, WIN, WOUT, NPIX, WPAD, OPLANE;
  if (pairIdx < 450) {
    inp = xb; wA = wx; bn = bnx; out = xfh; nblk = pairIdx;
    HIN = 32; WIN = 32; WOUT = 30; NPIX = 900; WPAD = 32; OPLANE = 960;
  } else {
    inp = zb; wA = wz; bn = bnz; out = zfh; nblk = pairIdx - 450;
    HIN = 16; WIN = 16; WOUT = 14; NPIX = 196; WPAD = 16; OPLANE = 224;
  }
  const int tid = threadIdx.x;
  const int wid = tid >> 6, lane = tid & 63;
  const int wm = (wid >> 1) << 6, wn = (wid & 1) << 6;
  const int q = lane >> 4, lm = lane & 15;
  const int sr = lane >> 3, sc = lane & 7;
  const int swz = (sc ^ sr) << 3;
  const int mbase = mblk << 7;

  int arow[4], brow[4];
#pragma unroll
  for (int l = 0; l < 4; ++l) {
    int rr = (wid << 5) + (l << 3) + sr;
    arow[l] = ((mbase + rr) << 8) + swz;
    int n = (nblk << 7) + rr;
    int b = n / NPIX, rem = n - b * NPIX;
    int oh = rem / WOUT, ow = rem - oh * WOUT;
    brow[l] = (((b * HIN + oh) * WIN + ow) << 8) + swz;
  }

  f32x4 acc[4][4] = {};
  const int cA0 = (q ^ (lm & 7)) << 3;

  for (int kt = 0; kt < 36; ++kt) {
    const int cinb = kt / 9;
    const int khw = kt - cinb * 9;
    const int cin0 = cinb << 6;
    const int kh = khw / 3, kw = khw - kh * 3;
    const int wofs = (khw << 16) + cin0;
    const int iofs = ((kh * WIN + kw) << 8) + cin0;
#pragma unroll
    for (int l = 0; l < 4; ++l) {
      const int ldso = ((wid << 5) + (l << 3)) << 6;
      gl_lds16(wA + wofs + arow[l], As + ldso);
      gl_lds16(inp + iofs + brow[l], Bs + ldso);
    }
    __syncthreads();
#pragma unroll
    for (int h = 0; h < 2; ++h) {
      const int co = cA0 ^ (h << 5);
      half8 af[4], bf[4];
#pragma unroll
      for (int f = 0; f < 4; ++f) {
        af[f] = *(const half8*)&As[((wm + (f << 4) + lm) << 6) + co];
        bf[f] = *(const half8*)&Bs[((wn + (f << 4) + lm) << 6) + co];
      }
#pragma unroll
      for (int fm = 0; fm < 4; ++fm)
#pragma unroll
        for (int fn = 0; fn < 4; ++fn)
          acc[fm][fn] =
              __builtin_amdgcn_mfma_f32_16x16x32_f16(af[fm], bf[fn], acc[fm][fn], 0, 0, 0);
    }
    __syncthreads();
  }

#pragma unroll
  for (int fn = 0; fn < 4; ++fn) {
    int n_g = (nblk << 7) + wn + (fn << 4) + lm;
    int b = n_g / NPIX, rem = n_g - b * NPIX;
    int oh = rem / WOUT, ow = rem - oh * WOUT;
    f16* op = out + (size_t)(b << 8) * OPLANE + oh * WPAD + ow;
#pragma unroll
    for (int fm = 0; fm < 4; ++fm) {
      int m0 = mbase + wm + (fm << 4) + (q << 2);
#pragma unroll
      for (int rg = 0; rg < 4; ++rg) {
        int m = m0 + rg;
        op[(size_t)m * OPLANE] = (f16)(acc[fm][fn][rg] * bn[m] + bn[256 + m]);
      }
    }
  }
}

// ---------------- depthwise xcorr v5: full-ox-row per thread ----------------
// 15 channels/block, 17 threads/channel (thread = one oy row, 17 ox outputs).
// Per u-iter: 4 half8 x-reads + 2 half8 z-reads (z broadcast within 17-lane group)
// feed 119 fdot2 -> LDS bytes/output /3.3 vs v4. x staged at row-stride 40
// ((6*lc+5*oy) mod 8 covers all 8 bank groups -> spread). Numerics: identical
// pair-association as v4 fdot2 (absmax unchanged).
static constexpr int XROWS = 30;
static constexpr int XSTR  = 40;            // f16; 80B rows -> bank spread
static constexpr int XCHN  = XROWS * XSTR;  // 1200 f16/channel
static constexpr int ZCHN  = 224;           // 14*16 f16/channel
static constexpr int CPB   = 15;            // channels per block

__global__ __launch_bounds__(256) void xcorr_dw3(const f16* __restrict__ zfh,
                                                 const f16* __restrict__ xfh,
                                                 float* __restrict__ out) {
  __shared__ alignas(16) f16 xs[CPB * XCHN];  // 36000 B
  __shared__ alignas(16) f16 zs[CPB * ZCHN];  //  6720 B
  const int t = threadIdx.x;
  const int ch0 = blockIdx.x * CPB;

  // stage x: 15ch x 30 rows x 4 half8 (cols 0..31 of the [30][32] plane)
  for (int i = t; i < CPB * 30 * 4; i += 256) {
    int ch = i / 120, rem = i - ch * 120;
    int row = rem >> 2, c8 = (rem & 3) << 3;
    if (ch0 + ch < 16384)
      *(half8*)(xs + ch * XCHN + row * XSTR + c8) =
          *(const half8*)(xfh + (size_t)(ch0 + ch) * 960 + row * 32 + c8);
  }
  // stage z: 15ch x 28 half8
  for (int i = t; i < CPB * 28; i += 256) {
    int ch = i / 28, rem = i - ch * 28;
    if (ch0 + ch < 16384)
      *(half8*)(zs + ch * ZCHN + rem * 8) =
          *(const half8*)(zfh + (size_t)(ch0 + ch) * 224 + rem * 8);
  }
  __syncthreads();

  int lc = t / 17;                    // 0..15 (15 = idle lane 255)
  const int oy = t - lc * 17;
  const bool ok = (lc < CPB) && (ch0 + lc < 16384);
  if (lc >= CPB) lc = CPB - 1;
  const f16* xbp = xs + lc * XCHN;
  const f16* zbp = zs + lc * ZCHN;

  float acc[17];
#pragma unroll
  for (int j = 0; j < 17; ++j) acc[j] = 0.f;

#if HAVE_FDOT2
  union X32 { half8 v8[4]; fp16x2 h2[16]; };
  union Z16 { half8 v8[2]; fp16x2 h2[8]; };
  for (int u = 0; u < 14; ++u) {
    X32 xl;
#pragma unroll
    for (int k = 0; k < 4; ++k)
      xl.v8[k] = *(const half8*)(xbp + (oy + u) * XSTR + (k << 3));
    Z16 zl;
    zl.v8[0] = *(const half8*)(zbp + u * 16);
    zl.v8[1] = *(const half8*)(zbp + u * 16 + 8);
    fp16x2 xo[15];
#pragma unroll
    for (int m = 0; m < 15; ++m) { xo[m][0] = xl.h2[m][1]; xo[m][1] = xl.h2[m + 1][0]; }
    // acc[2t]   += sum_m fdot2(z2[m], xe[m+t])   t=0..8
    // acc[2t+1] += sum_m fdot2(z2[m], xo[m+t])   t=0..7
#pragma unroll
    for (int m = 0; m < 7; ++m) {
#pragma unroll
      for (int tt = 0; tt < 8; ++tt) {
        acc[2 * tt]     = __builtin_amdgcn_fdot2(zl.h2[m], xl.h2[m + tt], acc[2 * tt], false);
        acc[2 * tt + 1] = __builtin_amdgcn_fdot2(zl.h2[m], xo[m + tt],    acc[2 * tt + 1], false);
      }
      acc[16] = __builtin_amdgcn_fdot2(zl.h2[m], xl.h2[m + 8], acc[16], false);
    }
  }
#else
  for (int u = 0; u < 14; ++u) {
    float xr[30];
#pragma unroll
    for (int k = 0; k < 4; ++k) {
      half8 h = *(const half8*)(xbp + (oy + u) * XSTR + (k << 3));
#pragma unroll
      for (int e = 0; e < 8; ++e)
        if (k * 8 + e < 30) xr[k * 8 + e] = (float)h[e];
    }
    float zc[14];
    {
      half8 z0 = *(const half8*)(zbp + u * 16);
      half8 z1 = *(const half8*)(zbp + u * 16 + 8);
#pragma unroll
      for (int e = 0; e < 8; ++e) zc[e] = (float)z0[e];
#pragma unroll
      for (int e = 0; e < 6; ++e) zc[8 + e] = (float)z1[e];
    }
#pragma unroll
    for (int v = 0; v < 14; ++v)
#pragma unroll
      for (int j = 0; j < 17; ++j) acc[j] = fmaf(zc[v], xr[v + j], acc[j]);
  }
#endif

  if (ok) {
    float* op = out + (size_t)(ch0 + lc) * 289 + oy * 17;
#pragma unroll
    for (int j = 0; j < 17; ++j) op[j] = acc[j];
  }
}

extern "C" void kernel_launch(void* const* d_in, const int* in_sizes, int n_in,
                              void* d_out, int out_size, void* d_ws, size_t ws_size,
                              hipStream_t stream) {
  const float* z = (const float*)d_in[0];
  const float* x = (const float*)d_in[1];
  const float* w_z = (const float*)d_in[2];
  const float* w_x = (const float*)d_in[3];
  const float* gamma_z = (const float*)d_in[4];
  const float* beta_z = (const float*)d_in[5];
  const float* mean_z = (const float*)d_in[6];
  const float* var_z = (const float*)d_in[7];
  const float* gamma_x = (const float*)d_in[8];
  const float* beta_x = (const float*)d_in[9];
  const float* mean_x = (const float*)d_in[10];
  const float* var_x = (const float*)d_in[11];

  char* ws = (char*)d_ws;
  f16* xb = (f16*)(ws + OFF_XB);
  f16* zb = (f16*)(ws + OFF_ZB);
  f16* wxA = (f16*)(ws + OFF_WX);
  f16* wzA = (f16*)(ws + OFF_WZ);
  float* bnx = (float*)(ws + OFF_BNX);
  float* bnz = (float*)(ws + OFF_BNZ);
  f16* xfh = (f16*)(ws + OFF_XFH);
  f16* zfh = (f16*)(ws + OFF_ZFH);
  float* out = (float*)d_out;

  prep_all<<<12801, 256, 0, stream>>>(x, z, w_x, w_z,
                                      gamma_x, beta_x, mean_x, var_x,
                                      gamma_z, beta_z, mean_z, var_z,
                                      xb, zb, wxA, wzA, bnx, bnz);

  // 548 (pair) x 2 (mblk) tiles, padded to 1104 = 69*16 for the XCD permutation
  conv_gemm_u<<<1104, 256, 0, stream>>>(xb, zb, wxA, wzA, bnx, bnz, xfh, zfh);

  xcorr_dw3<<<(16384 + CPB - 1) / CPB, 256, 0, stream>>>(zfh, xfh, out);
}